// Round 14
// baseline (127.169 us; speedup 1.0000x reference)
//
#include <hip/hip_runtime.h>
#include <hip/hip_bf16.h>
#include <cstdint>

#define NB   64
#define CIN  1024
#define HWSP 196
#define MTOT 12544
#define PL   256
#define COUT 1024

using f32x4 = __attribute__((ext_vector_type(4))) float;
using s16x8 = __attribute__((ext_vector_type(8))) short;

static __device__ __forceinline__ short f2bf(float f) {
  union { __hip_bfloat16 h; short s; } u;
  u.h = __float2bfloat16(f);
  return u.s;
}
static __device__ __forceinline__ float bf2f(short s) {
  union { float f; unsigned u; } x;
  x.u = ((unsigned)(unsigned short)s) << 16;
  return x.f;
}

static __device__ __forceinline__ void gload16(const void* g, void* l) {
  __builtin_amdgcn_global_load_lds((const __attribute__((address_space(1))) void*)g,
                                   (__attribute__((address_space(3))) void*)l, 16, 0, 0);
}

// ------------- merged prep: x-transpose | weight cast/reorder | stats zero ---
__global__ __launch_bounds__(256) void k_prep(const float* __restrict__ x,
                                              const float* __restrict__ w1,
                                              const float* __restrict__ w2,
                                              const float* __restrict__ w3,
                                              short* __restrict__ xb,
                                              short* __restrict__ w1b,
                                              short* __restrict__ w2b,
                                              short* __restrict__ w3b,
                                              float* __restrict__ statszero) {
  const int bid = blockIdx.x;
  if (bid < 2048) {
    __shared__ float tile[32][197];
    const int n = bid >> 5;
    const int c0 = (bid & 31) * 32;
    for (int idx = threadIdx.x; idx < 32 * 196; idx += 256) {
      int cl = idx / 196, hw = idx % 196;
      tile[cl][hw] = x[((size_t)(n * CIN + c0 + cl)) * HWSP + hw];
    }
    __syncthreads();
    for (int idx = threadIdx.x; idx < 196 * 32; idx += 256) {
      int hw = idx >> 5, cl = idx & 31;
      xb[((size_t)(n * HWSP + hw)) * CIN + c0 + cl] = f2bf(tile[cl][hw]);
    }
  } else if (bid < 6400) {
    int i = (bid - 2048) * 256 + threadIdx.x;
    if (i < 262144) w1b[i] = f2bf(w1[i]);
    int j = i - 262144;
    if (j >= 0 && j < 589824) {
      int co = j / 2304, rem = j % 2304;
      int d = rem >> 8, ci = rem & 255;
      w2b[j] = f2bf(w2[((size_t)(co * 256 + ci)) * 9 + d]);
    }
    int k = i - 851968;
    if (k >= 0 && k < 262144) w3b[k] = f2bf(w3[k]);
  } else {
    for (int k = threadIdx.x; k < 3136; k += 256) statszero[k] = 0.f;
  }
}

// ---------------- generic MFMA GEMM (R9/R13 structure) for conv1/conv3 -------
static __device__ __forceinline__ int swz(int row, int k16, int bk) {
  return row * (bk * 2) + (((unsigned)(k16 ^ (row & 7))) << 4);
}

template <int K, int BK>
__global__ __launch_bounds__(256) void gemm_kernel(const short* __restrict__ A,
                                                   const short* __restrict__ Bw,
                                                   const float* __restrict__ bias,
                                                   short* __restrict__ Yb,
                                                   float* __restrict__ st,
                                                   int Nc) {
  constexpr int NKT = K / BK;
  constexpr int KCH = BK / 8;
  constexpr int QN = BK / 16;
  constexpr int TBYTES = 128 * BK * 2;
  __shared__ __align__(16) char lds[2][2 * TBYTES];

  const int m0 = blockIdx.x * 128;
  const int n0 = blockIdx.y * 128;
  const int t = threadIdx.x;
  const int lane = t & 63, wid = t >> 6;
  const int wm = wid >> 1, wn = wid & 1;
  const int g = lane >> 4, r = lane & 15;

  const short* aSrc[QN];
  const short* bSrc[QN];
#pragma unroll
  for (int q = 0; q < QN; ++q) {
    int chunk = t + q * 256;
    int row = chunk / KCH;
    int k16s = (chunk % KCH) ^ (row & 7);
    aSrc[q] = A + (size_t)(m0 + row) * K + k16s * 8;
    bSrc[q] = Bw + (size_t)(n0 + row) * K + k16s * 8;
  }

  auto stage = [&](int buf, int kt) {
    const int k0 = kt * BK;
    char* dA = &lds[buf][0];
    char* dB = &lds[buf][TBYTES];
#pragma unroll
    for (int q = 0; q < QN; ++q)
      gload16(aSrc[q] + k0, dA + (t + q * 256) * 16);
#pragma unroll
    for (int q = 0; q < QN; ++q)
      gload16(bSrc[q] + k0, dB + (t + q * 256) * 16);
  };

  f32x4 acc[4][4] = {};
  auto compute = [&](int buf) {
    char* baseA = &lds[buf][0];
    char* baseB = &lds[buf][TBYTES];
#pragma unroll
    for (int ks = 0; ks < BK / 32; ++ks) {
      s16x8 af[4], bfr[4];
#pragma unroll
      for (int i = 0; i < 4; ++i)
        af[i] = *(const s16x8*)(baseA + swz(wm * 64 + i * 16 + r, ks * 4 + g, BK));
#pragma unroll
      for (int j = 0; j < 4; ++j)
        bfr[j] = *(const s16x8*)(baseB + swz(wn * 64 + j * 16 + r, ks * 4 + g, BK));
#pragma unroll
      for (int i = 0; i < 4; ++i)
#pragma unroll
        for (int j = 0; j < 4; ++j)
          acc[i][j] = __builtin_amdgcn_mfma_f32_16x16x32_bf16(af[i], bfr[j], acc[i][j], 0, 0, 0);
    }
  };

  stage(0, 0);
  int cur = 0;
#pragma unroll 1
  for (int kt = 0; kt < NKT - 1; ++kt) {
    stage(cur ^ 1, kt + 1);
    if constexpr (BK == 64)
      asm volatile("s_waitcnt vmcnt(8)" ::: "memory");
    else
      asm volatile("s_waitcnt vmcnt(16)" ::: "memory");
    __builtin_amdgcn_s_barrier();
    compute(cur);
    asm volatile("" ::: "memory");
    __builtin_amdgcn_s_barrier();
    cur ^= 1;
  }
  asm volatile("s_waitcnt vmcnt(0)" ::: "memory");
  __builtin_amdgcn_s_barrier();
  compute(cur);

#pragma unroll
  for (int j = 0; j < 4; ++j) {
    int col = n0 + wn * 64 + j * 16 + r;
    float bv = bias[col];
    float ps = 0.f, pq = 0.f;
#pragma unroll
    for (int i = 0; i < 4; ++i) {
      int row_base = m0 + wm * 64 + i * 16 + g * 4;
#pragma unroll
      for (int rr = 0; rr < 4; ++rr) {
        float v = acc[i][j][rr] + bv;
        ps += v;
        pq += v * v;
        Yb[(size_t)(row_base + rr) * Nc + col] = f2bf(v);
      }
    }
    ps += __shfl_xor(ps, 16);
    ps += __shfl_xor(ps, 32);
    pq += __shfl_xor(pq, 16);
    pq += __shfl_xor(pq, 32);
    if (lane < 16) {
      atomicAdd(&st[col], ps);
      atomicAdd(&st[Nc + col], pq);
    }
  }
}

// ---------------- conv2: spatial-reuse 3x3 (A staged ONCE, 9 taps via rows) --
// y2[m][co] = sum_{d,ci} y1[m + off(d)][ci] * w2b[co][d*256+ci]  (zero OOB)
// Key identity: tap row m' = m + (dh-1)*14 + (dw-1) when (hh,ww) in-image, and
// m' always falls in [lo, hi) = [max(0,m0-15), min(12544,m0+143)). So stage
// rows [lo,hi) of y1b once (<=158 rows, 512B each) + 1 zero row (idx 158);
// per lane per K-tile select LDS row = valid ? (m-lo)+off : 158.
// B: [128co][64k] double-buffered, staged per K-tile (kt linear in w2b).
// Row swizzle (both A rows and B): ((k16 ^ (row&7)) << 4) within the row.
__global__ __launch_bounds__(256) void k_conv2(const short* __restrict__ y1b,
                                               const short* __restrict__ w2b,
                                               const float* __restrict__ bias,
                                               short* __restrict__ Yb,
                                               float* __restrict__ st,
                                               const short* __restrict__ zerobuf) {
  __shared__ __align__(16) char ldsA[159 * 512];   // 81.4 KB, resident
  __shared__ __align__(16) char ldsB[2][16384];    // B dbuf

  const int m0 = blockIdx.x * 128;
  const int n0 = blockIdx.y * 128;
  const int t = threadIdx.x;
  const int lane = t & 63, wid = t >> 6;
  const int wm = wid >> 1, wn = wid & 1;
  const int g = lane >> 4, r = lane & 15;

  const int lo = (m0 >= 15) ? m0 - 15 : 0;
  const int hi = (m0 + 143 < MTOT) ? m0 + 143 : MTOT;
  const int nch = (hi - lo) * 32;   // 16B chunks of A to stage

  // ---- stage A rows once (linear dest, inverse-swizzled source)
#pragma unroll
  for (int q = 0; q < 20; ++q) {
    int chunk = t + q * 256;
    if (chunk < nch) {
      int row = chunk >> 5, k16d = chunk & 31;
      int k16s = k16d ^ (row & 7);
      gload16(y1b + (size_t)(lo + row) * 256 + k16s * 8, ldsA + chunk * 16);
    }
  }
  if (t < 32) gload16(zerobuf, ldsA + (158 * 32 + t) * 16);  // zero row

  // ---- B staging sources (4 chunks/thread per K-tile)
  const short* bSrc[4];
#pragma unroll
  for (int q = 0; q < 4; ++q) {
    int chunk = t + q * 256;
    int row = chunk >> 3;
    int k16s = (chunk & 7) ^ (row & 7);
    bSrc[q] = w2b + (size_t)(n0 + row) * 2304 + k16s * 8;
  }
  auto stageB = [&](int buf, int kt) {
#pragma unroll
    for (int q = 0; q < 4; ++q)
      gload16(bSrc[q] + kt * 64, ldsB[buf] + (t + q * 256) * 16);
  };

  // ---- per-lane output-row coords
  int mrel[4], hc[4], wc[4];
#pragma unroll
  for (int i = 0; i < 4; ++i) {
    int m = m0 + wm * 64 + i * 16 + r;
    mrel[i] = m - lo;
    int hw = m % 196;
    hc[i] = hw / 14;
    wc[i] = hw - hc[i] * 14;
  }

  stageB(0, 0);
  asm volatile("s_waitcnt vmcnt(0)" ::: "memory");
  __builtin_amdgcn_s_barrier();

  f32x4 acc[4][4] = {};
  int cur = 0;
#pragma unroll 1
  for (int kt = 0; kt < 36; ++kt) {
    int d = kt >> 2, cb = kt & 3;            // tap, 64-ch block
    int dh = d / 3, dw = d - dh * 3;         // uniform (SALU)
    int off = (dh - 1) * 14 + (dw - 1);
    int rowi[4];
#pragma unroll
    for (int i = 0; i < 4; ++i) {
      int hh = hc[i] + dh - 1, ww = wc[i] + dw - 1;
      bool v = ((unsigned)hh < 14u) && ((unsigned)ww < 14u);
      rowi[i] = v ? (mrel[i] + off) : 158;
    }
    if (kt < 35) stageB(cur ^ 1, kt + 1);
    asm volatile("s_waitcnt vmcnt(4)" ::: "memory");   // B(kt) landed
    __builtin_amdgcn_s_barrier();
#pragma unroll
    for (int ks = 0; ks < 2; ++ks) {
      s16x8 af[4], bfr[4];
#pragma unroll
      for (int i = 0; i < 4; ++i) {
        int k16 = cb * 8 + ks * 4 + g;
        af[i] = *(const s16x8*)(ldsA + rowi[i] * 512 +
                                (((unsigned)(k16 ^ (rowi[i] & 7))) << 4));
      }
#pragma unroll
      for (int j = 0; j < 4; ++j)
        bfr[j] = *(const s16x8*)(ldsB[cur] + swz(wn * 64 + j * 16 + r, ks * 4 + g, 64));
#pragma unroll
      for (int i = 0; i < 4; ++i)
#pragma unroll
        for (int j = 0; j < 4; ++j)
          acc[i][j] = __builtin_amdgcn_mfma_f32_16x16x32_bf16(af[i], bfr[j], acc[i][j], 0, 0, 0);
    }
    asm volatile("" ::: "memory");
    __builtin_amdgcn_s_barrier();   // reads done before next stage into cur^1's partner
    cur ^= 1;
  }

  // epilogue: bias, bf16 store, stats atomics
#pragma unroll
  for (int j = 0; j < 4; ++j) {
    int col = n0 + wn * 64 + j * 16 + r;
    float bv = bias[col];
    float ps = 0.f, pq = 0.f;
#pragma unroll
    for (int i = 0; i < 4; ++i) {
      int row_base = m0 + wm * 64 + i * 16 + g * 4;
#pragma unroll
      for (int rr = 0; rr < 4; ++rr) {
        float v = acc[i][j][rr] + bv;
        ps += v;
        pq += v * v;
        Yb[(size_t)(row_base + rr) * 256 + col] = f2bf(v);
      }
    }
    ps += __shfl_xor(ps, 16);
    ps += __shfl_xor(ps, 32);
    pq += __shfl_xor(pq, 16);
    pq += __shfl_xor(pq, 32);
    if (lane < 16) {
      atomicAdd(&st[col], ps);
      atomicAdd(&st[256 + col], pq);
    }
  }
}

// ------- in-place: yb = bf16(relu(sc*yb+sh)), C=256; sc/sh computed here -----
__global__ __launch_bounds__(256) void k_apply(short* __restrict__ Yb,
                                               const float* __restrict__ st,
                                               const float* __restrict__ gamma,
                                               const float* __restrict__ beta) {
  __shared__ float lsc[256], lsh[256];
  const int t = threadIdx.x;
  {
    const float inv = 1.0f / 12544.0f;
    float mean = st[t] * inv;
    float var = st[256 + t] * inv - mean * mean;
    float s = gamma[t] * rsqrtf(var + 1e-5f);
    lsc[t] = s;
    lsh[t] = beta[t] - mean * s;
  }
  __syncthreads();
  size_t i8 = ((size_t)blockIdx.x * 256 + t) * 8;
  s16x8 v = *(const s16x8*)(Yb + i8);
  int c0 = (int)(i8 & 255);
#pragma unroll
  for (int e = 0; e < 8; ++e) {
    float f = bf2f(v[e]);
    v[e] = f2bf(fmaxf(lsc[c0 + e] * f + lsh[c0 + e], 0.f));
  }
  *(s16x8*)(Yb + i8) = v;
}

// -------- final: out = relu(x + softplus(rs)*bn3(y3)); sc/sh in-kernel -------
__global__ __launch_bounds__(256) void k_final(const float* __restrict__ x,
                                               const short* __restrict__ y3b,
                                               const float* __restrict__ st,
                                               const float* __restrict__ gamma,
                                               const float* __restrict__ beta,
                                               const float* __restrict__ rs,
                                               float* __restrict__ out) {
  __shared__ short ytile[64][198];
  __shared__ float lsc[64], lsh[64];
  const int n = blockIdx.x;
  const int co0 = blockIdx.y * 64;
  const int t = threadIdx.x;
  if (t < 64) {
    const float inv = 1.0f / 12544.0f;
    int c = co0 + t;
    float mean = st[c] * inv;
    float var = st[1024 + c] * inv - mean * mean;
    float s = gamma[c] * rsqrtf(var + 1e-5f);
    lsc[t] = s;
    lsh[t] = beta[c] - mean * s;
  }
#pragma unroll
  for (int iter = 0; iter < 49; ++iter) {
    int idx = iter * 256 + t;
    int hw = idx >> 6, c = idx & 63;
    ytile[c][hw] = y3b[((size_t)(n * 196 + hw)) * 1024 + co0 + c];
  }
  __syncthreads();
  float z = rs[0];
  float s = fmaxf(z, 0.f) + log1pf(expf(-fabsf(z)));  // stable softplus
#pragma unroll
  for (int iter = 0; iter < 49; ++iter) {
    int idx = iter * 256 + t;
    int co = idx / 196, hw = idx - co * 196;
    size_t xi = ((size_t)(n * 1024 + co0 + co)) * 196 + hw;
    float v = bf2f(ytile[co][hw]);
    float o = x[xi] + s * (lsc[co] * v + lsh[co]);
    out[xi] = fmaxf(o, 0.f);
  }
}

extern "C" void kernel_launch(void* const* d_in, const int* in_sizes, int n_in,
                              void* d_out, int out_size, void* d_ws, size_t ws_size,
                              hipStream_t stream) {
  const float* x   = (const float*)d_in[0];
  const float* w1  = (const float*)d_in[1];
  const float* b1  = (const float*)d_in[2];
  const float* g1  = (const float*)d_in[3];
  const float* be1 = (const float*)d_in[4];
  const float* w2  = (const float*)d_in[5];
  const float* b2  = (const float*)d_in[6];
  const float* g2  = (const float*)d_in[7];
  const float* be2 = (const float*)d_in[8];
  const float* w3  = (const float*)d_in[9];
  const float* b3  = (const float*)d_in[10];
  const float* g3  = (const float*)d_in[11];
  const float* be3 = (const float*)d_in[12];
  const float* rs  = (const float*)d_in[13];
  float* out = (float*)d_out;
  char* ws = (char*)d_ws;

  size_t off = 0;
  auto alloc = [&](size_t bytes) {
    size_t o = off;
    off += (bytes + 255) & ~(size_t)255;
    return o;
  };
  short* xb  = (short*)(ws + alloc((size_t)MTOT * CIN * 2));
  short* w1b = (short*)(ws + alloc((size_t)262144 * 2));
  short* w2b = (short*)(ws + alloc((size_t)589824 * 2));
  short* w3b = (short*)(ws + alloc((size_t)262144 * 2));
  short* y1b = (short*)(ws + alloc((size_t)MTOT * PL * 2));
  short* y2b = (short*)(ws + alloc((size_t)MTOT * PL * 2));
  short* y3b = (short*)(ws + alloc((size_t)MTOT * COUT * 2));
  float* stats = (float*)(ws + alloc(12288 + 256));
  float* stat1 = stats, *stat2 = stats + 512, *stat3 = stats + 1024;
  short* zerobuf = (short*)(stats + 3072);

  k_prep<<<6401, 256, 0, stream>>>(x, w1, w2, w3, xb, w1b, w2b, w3b, stats);

  // conv1: 1x1 reduce (K=1024 -> 256), BK=128
  gemm_kernel<1024, 128><<<dim3(98, 2), 256, 0, stream>>>(xb, w1b, b1, y1b, stat1, 256);
  k_apply<<<1568, 256, 0, stream>>>(y1b, stat1, g1, be1);

  // conv2: 3x3 spatial-reuse (A staged once, 9 taps from LDS rows)
  k_conv2<<<dim3(98, 2), 256, 0, stream>>>(y1b, w2b, b2, y2b, stat2, zerobuf);
  k_apply<<<1568, 256, 0, stream>>>(y2b, stat2, g2, be2);

  // conv3: 1x1 expand (K=256 -> 1024), BK=64
  gemm_kernel<256, 64><<<dim3(98, 8), 256, 0, stream>>>(y2b, w3b, b3, y3b, stat3, 1024);

  // residual + relu (+ bn3 finalize in-kernel)
  k_final<<<dim3(64, 16), 256, 0, stream>>>(x, y3b, stat3, g3, be3, rs, out);
}

// Round 15
// 125.651 us; speedup vs baseline: 1.0121x; 1.0121x over previous
//
#include <hip/hip_runtime.h>
#include <hip/hip_bf16.h>
#include <cstdint>

#define NB   64
#define CIN  1024
#define HWSP 196
#define MTOT 12544
#define PL   256
#define COUT 1024

using f32x4 = __attribute__((ext_vector_type(4))) float;
using s16x8 = __attribute__((ext_vector_type(8))) short;

static __device__ __forceinline__ short f2bf(float f) {
  union { __hip_bfloat16 h; short s; } u;
  u.h = __float2bfloat16(f);
  return u.s;
}
static __device__ __forceinline__ float bf2f(short s) {
  union { float f; unsigned u; } x;
  x.u = ((unsigned)(unsigned short)s) << 16;
  return x.f;
}

static __device__ __forceinline__ void gload16(const void* g, void* l) {
  __builtin_amdgcn_global_load_lds((const __attribute__((address_space(1))) void*)g,
                                   (__attribute__((address_space(3))) void*)l, 16, 0, 0);
}

// ------------- merged prep: x-transpose | weight cast/reorder | stats zero ---
__global__ __launch_bounds__(256) void k_prep(const float* __restrict__ x,
                                              const float* __restrict__ w1,
                                              const float* __restrict__ w2,
                                              const float* __restrict__ w3,
                                              short* __restrict__ xb,
                                              short* __restrict__ w1b,
                                              short* __restrict__ w2b,
                                              short* __restrict__ w3b,
                                              float* __restrict__ statszero) {
  const int bid = blockIdx.x;
  if (bid < 2048) {
    __shared__ float tile[32][197];
    const int n = bid >> 5;
    const int c0 = (bid & 31) * 32;
    for (int idx = threadIdx.x; idx < 32 * 196; idx += 256) {
      int cl = idx / 196, hw = idx % 196;
      tile[cl][hw] = x[((size_t)(n * CIN + c0 + cl)) * HWSP + hw];
    }
    __syncthreads();
    for (int idx = threadIdx.x; idx < 196 * 32; idx += 256) {
      int hw = idx >> 5, cl = idx & 31;
      xb[((size_t)(n * HWSP + hw)) * CIN + c0 + cl] = f2bf(tile[cl][hw]);
    }
  } else if (bid < 6400) {
    int i = (bid - 2048) * 256 + threadIdx.x;
    if (i < 262144) w1b[i] = f2bf(w1[i]);
    int j = i - 262144;
    if (j >= 0 && j < 589824) {
      int co = j / 2304, rem = j % 2304;
      int d = rem >> 8, ci = rem & 255;
      w2b[j] = f2bf(w2[((size_t)(co * 256 + ci)) * 9 + d]);
    }
    int k = i - 851968;
    if (k >= 0 && k < 262144) w3b[k] = f2bf(w3[k]);
  } else {
    for (int k = threadIdx.x; k < 3136; k += 256) statszero[k] = 0.f;
  }
}

// ---------------- MFMA GEMM: fine-interleaved 2-sub-phase schedule -----------
// Tile 128x128x64; 4 waves (2x2), per-wave 64x64, acc[4][4]; dbuf LDS.
// Per K-tile kt (loop-top outstanding VM ops/thread = 8, tile kt's):
//   stage A-half(kt+1)  [+4 -> 12]
//   vmcnt(4)            [retires exactly kt's 8]
//   s_barrier           [kt visible to all waves]
//   ds_read frags ks=0 ; setprio(1) 16 MFMA setprio(0)
//   stage B-half(kt+1)  [-> outstanding <= 8]
//   ds_read frags ks=1 ; setprio(1) 16 MFMA setprio(0)
//   s_barrier           [reads of kt done (MFMA data-dep) before overwrite]
// No sched_barrier anywhere (m141); lgkm waits are compiler-managed (plain
// C++ LDS derefs). vmcnt never drains to 0 until the final tile (T4).
// LDS read swizzle: row*128 + ((k16^(row&7))<<4); staging uses linear LDS
// dest + inverse-swizzled global source (rule #21).
static __device__ __forceinline__ int swz(int row, int k16) {
  return row * 128 + (((unsigned)(k16 ^ (row & 7))) << 4);
}

template <int MODE, int K>
__global__ __launch_bounds__(256) void gemm_kernel(const short* __restrict__ A,
                                                   const short* __restrict__ Bw,
                                                   const float* __restrict__ bias,
                                                   short* __restrict__ Yb,
                                                   float* __restrict__ st,
                                                   int Nc,
                                                   const short* __restrict__ zerobuf) {
  __shared__ __align__(16) char lds[2][32768];  // per buf: A 16KB | B 16KB
  constexpr int NKT = K >> 6;

  const int m0 = blockIdx.x * 128;
  const int n0 = blockIdx.y * 128;
  const int t = threadIdx.x;
  const int lane = t & 63, wid = t >> 6;
  const int wm = wid >> 1, wn = wid & 1;
  const int g = lane >> 4, r = lane & 15;

  const short* aSrc[4];
  int aN[4], aH[4], aW[4], aCi[4];
  const short* bSrc[4];
#pragma unroll
  for (int q = 0; q < 4; ++q) {
    int chunk = t + q * 256;
    int row = chunk >> 3;
    int k16s = (chunk & 7) ^ (row & 7);
    if (MODE == 0) {
      aSrc[q] = A + (size_t)(m0 + row) * K + k16s * 8;
    } else {
      int m = m0 + row;
      int n_ = m / 196;
      int hw = m - n_ * 196;
      aN[q] = n_;
      aH[q] = hw / 14;
      aW[q] = hw - aH[q] * 14;
      aCi[q] = k16s * 8;
    }
    bSrc[q] = Bw + (size_t)(n0 + row) * K + k16s * 8;
  }

  auto stageA = [&](int buf, int kt) {
    const int k0 = kt << 6;
    char* dA = &lds[buf][0];
#pragma unroll
    for (int q = 0; q < 4; ++q) {
      const short* s;
      if (MODE == 0) {
        s = aSrc[q] + k0;
      } else {
        int d = kt >> 2;
        int dh = d / 3, dw = d - dh * 3;
        int hh = aH[q] + dh - 1, ww = aW[q] + dw - 1;
        s = ((unsigned)hh < 14u && (unsigned)ww < 14u)
                ? A + ((size_t)(aN[q] * 196 + hh * 14 + ww)) * 256 + (k0 & 255) + aCi[q]
                : zerobuf;
      }
      gload16(s, dA + (t + q * 256) * 16);
    }
  };
  auto stageB = [&](int buf, int kt) {
    const int k0 = kt << 6;
    char* dB = &lds[buf][16384];
#pragma unroll
    for (int q = 0; q < 4; ++q)
      gload16(bSrc[q] + k0, dB + (t + q * 256) * 16);
  };

  f32x4 acc[4][4] = {};
  auto computeKS = [&](int buf, int ks) {
    char* baseA = &lds[buf][0];
    char* baseB = &lds[buf][16384];
    s16x8 af[4], bfr[4];
#pragma unroll
    for (int i = 0; i < 4; ++i)
      af[i] = *(const s16x8*)(baseA + swz(wm * 64 + i * 16 + r, ks * 4 + g));
#pragma unroll
    for (int j = 0; j < 4; ++j)
      bfr[j] = *(const s16x8*)(baseB + swz(wn * 64 + j * 16 + r, ks * 4 + g));
    __builtin_amdgcn_s_setprio(1);
#pragma unroll
    for (int i = 0; i < 4; ++i)
#pragma unroll
      for (int j = 0; j < 4; ++j)
        acc[i][j] = __builtin_amdgcn_mfma_f32_16x16x32_bf16(af[i], bfr[j], acc[i][j], 0, 0, 0);
    __builtin_amdgcn_s_setprio(0);
  };

  stageA(0, 0);
  stageB(0, 0);                       // outstanding = 8 (tile 0)
  int cur = 0;
#pragma unroll 1
  for (int kt = 0; kt < NKT - 1; ++kt) {
    stageA(cur ^ 1, kt + 1);                            // 12 outstanding
    asm volatile("s_waitcnt vmcnt(4)" ::: "memory");    // tile kt landed
    __builtin_amdgcn_s_barrier();
    computeKS(cur, 0);
    stageB(cur ^ 1, kt + 1);                            // <= 8 outstanding
    computeKS(cur, 1);
    asm volatile("" ::: "memory");
    __builtin_amdgcn_s_barrier();                       // kt reads done
    cur ^= 1;
  }
  asm volatile("s_waitcnt vmcnt(0)" ::: "memory");
  __builtin_amdgcn_s_barrier();
  computeKS(cur, 0);
  computeKS(cur, 1);

  // epilogue: bias, bf16 store, per-channel sum/sumsq -> atomics
#pragma unroll
  for (int j = 0; j < 4; ++j) {
    int col = n0 + wn * 64 + j * 16 + r;
    float bv = bias[col];
    float ps = 0.f, pq = 0.f;
#pragma unroll
    for (int i = 0; i < 4; ++i) {
      int row_base = m0 + wm * 64 + i * 16 + g * 4;
#pragma unroll
      for (int rr = 0; rr < 4; ++rr) {
        float v = acc[i][j][rr] + bv;
        ps += v;
        pq += v * v;
        Yb[(size_t)(row_base + rr) * Nc + col] = f2bf(v);
      }
    }
    ps += __shfl_xor(ps, 16);
    ps += __shfl_xor(ps, 32);
    pq += __shfl_xor(pq, 16);
    pq += __shfl_xor(pq, 32);
    if (lane < 16) {
      atomicAdd(&st[col], ps);
      atomicAdd(&st[Nc + col], pq);
    }
  }
}

// ------- in-place: yb = bf16(relu(sc*yb+sh)), C=256; sc/sh computed here -----
__global__ __launch_bounds__(256) void k_apply(short* __restrict__ Yb,
                                               const float* __restrict__ st,
                                               const float* __restrict__ gamma,
                                               const float* __restrict__ beta) {
  __shared__ float lsc[256], lsh[256];
  const int t = threadIdx.x;
  {
    const float inv = 1.0f / 12544.0f;
    float mean = st[t] * inv;
    float var = st[256 + t] * inv - mean * mean;
    float s = gamma[t] * rsqrtf(var + 1e-5f);
    lsc[t] = s;
    lsh[t] = beta[t] - mean * s;
  }
  __syncthreads();
  size_t i8 = ((size_t)blockIdx.x * 256 + t) * 8;
  s16x8 v = *(const s16x8*)(Yb + i8);
  int c0 = (int)(i8 & 255);
#pragma unroll
  for (int e = 0; e < 8; ++e) {
    float f = bf2f(v[e]);
    v[e] = f2bf(fmaxf(lsc[c0 + e] * f + lsh[c0 + e], 0.f));
  }
  *(s16x8*)(Yb + i8) = v;
}

// -------- final: out = relu(x + softplus(rs)*bn3(y3)); sc/sh in-kernel -------
__global__ __launch_bounds__(256) void k_final(const float* __restrict__ x,
                                               const short* __restrict__ y3b,
                                               const float* __restrict__ st,
                                               const float* __restrict__ gamma,
                                               const float* __restrict__ beta,
                                               const float* __restrict__ rs,
                                               float* __restrict__ out) {
  __shared__ short ytile[64][198];
  __shared__ float lsc[64], lsh[64];
  const int n = blockIdx.x;
  const int co0 = blockIdx.y * 64;
  const int t = threadIdx.x;
  if (t < 64) {
    const float inv = 1.0f / 12544.0f;
    int c = co0 + t;
    float mean = st[c] * inv;
    float var = st[1024 + c] * inv - mean * mean;
    float s = gamma[c] * rsqrtf(var + 1e-5f);
    lsc[t] = s;
    lsh[t] = beta[c] - mean * s;
  }
#pragma unroll
  for (int iter = 0; iter < 49; ++iter) {
    int idx = iter * 256 + t;
    int hw = idx >> 6, c = idx & 63;
    ytile[c][hw] = y3b[((size_t)(n * 196 + hw)) * 1024 + co0 + c];
  }
  __syncthreads();
  float z = rs[0];
  float s = fmaxf(z, 0.f) + log1pf(expf(-fabsf(z)));  // stable softplus
#pragma unroll
  for (int iter = 0; iter < 49; ++iter) {
    int idx = iter * 256 + t;
    int co = idx / 196, hw = idx - co * 196;
    size_t xi = ((size_t)(n * 1024 + co0 + co)) * 196 + hw;
    float v = bf2f(ytile[co][hw]);
    float o = x[xi] + s * (lsc[co] * v + lsh[co]);
    out[xi] = fmaxf(o, 0.f);
  }
}

extern "C" void kernel_launch(void* const* d_in, const int* in_sizes, int n_in,
                              void* d_out, int out_size, void* d_ws, size_t ws_size,
                              hipStream_t stream) {
  const float* x   = (const float*)d_in[0];
  const float* w1  = (const float*)d_in[1];
  const float* b1  = (const float*)d_in[2];
  const float* g1  = (const float*)d_in[3];
  const float* be1 = (const float*)d_in[4];
  const float* w2  = (const float*)d_in[5];
  const float* b2  = (const float*)d_in[6];
  const float* g2  = (const float*)d_in[7];
  const float* be2 = (const float*)d_in[8];
  const float* w3  = (const float*)d_in[9];
  const float* b3  = (const float*)d_in[10];
  const float* g3  = (const float*)d_in[11];
  const float* be3 = (const float*)d_in[12];
  const float* rs  = (const float*)d_in[13];
  float* out = (float*)d_out;
  char* ws = (char*)d_ws;

  size_t off = 0;
  auto alloc = [&](size_t bytes) {
    size_t o = off;
    off += (bytes + 255) & ~(size_t)255;
    return o;
  };
  short* xb  = (short*)(ws + alloc((size_t)MTOT * CIN * 2));
  short* w1b = (short*)(ws + alloc((size_t)262144 * 2));
  short* w2b = (short*)(ws + alloc((size_t)589824 * 2));
  short* w3b = (short*)(ws + alloc((size_t)262144 * 2));
  short* y1b = (short*)(ws + alloc((size_t)MTOT * PL * 2));
  short* y2b = (short*)(ws + alloc((size_t)MTOT * PL * 2));
  short* y3b = (short*)(ws + alloc((size_t)MTOT * COUT * 2));
  float* stats = (float*)(ws + alloc(12288 + 256));
  float* stat1 = stats, *stat2 = stats + 512, *stat3 = stats + 1024;
  short* zerobuf = (short*)(stats + 3072);

  k_prep<<<6401, 256, 0, stream>>>(x, w1, w2, w3, xb, w1b, w2b, w3b, stats);

  // conv1: 1x1 reduce (K=1024 -> 256)
  gemm_kernel<0, 1024><<<dim3(98, 2), 256, 0, stream>>>(xb, w1b, b1, y1b, stat1, 256, zerobuf);
  k_apply<<<1568, 256, 0, stream>>>(y1b, stat1, g1, be1);

  // conv2: 3x3 (K=2304 -> 256), im2col gather (0 bank conflicts)
  gemm_kernel<1, 2304><<<dim3(98, 2), 256, 0, stream>>>(y1b, w2b, b2, y2b, stat2, 256, zerobuf);
  k_apply<<<1568, 256, 0, stream>>>(y2b, stat2, g2, be2);

  // conv3: 1x1 expand (K=256 -> 1024)
  gemm_kernel<0, 256><<<dim3(98, 8), 256, 0, stream>>>(y2b, w3b, b3, y3b, stat3, 1024, zerobuf);

  // residual + relu (+ bn3 finalize in-kernel)
  k_final<<<dim3(64, 16), 256, 0, stream>>>(x, y3b, stat3, g3, be3, rs, out);
}

// Round 16
// 115.109 us; speedup vs baseline: 1.1048x; 1.0916x over previous
//
#include <hip/hip_runtime.h>
#include <hip/hip_bf16.h>
#include <cstdint>

#define NB   64
#define CIN  1024
#define HWSP 196
#define MTOT 12544
#define PL   256
#define COUT 1024

using f32x4 = __attribute__((ext_vector_type(4))) float;
using s16x8 = __attribute__((ext_vector_type(8))) short;

static __device__ __forceinline__ short f2bf(float f) {
  union { __hip_bfloat16 h; short s; } u;
  u.h = __float2bfloat16(f);
  return u.s;
}
static __device__ __forceinline__ float bf2f(short s) {
  union { float f; unsigned u; } x;
  x.u = ((unsigned)(unsigned short)s) << 16;
  return x.f;
}

static __device__ __forceinline__ void gload16(const void* g, void* l) {
  __builtin_amdgcn_global_load_lds((const __attribute__((address_space(1))) void*)g,
                                   (__attribute__((address_space(3))) void*)l, 16, 0, 0);
}

// ------------- merged prep: x-transpose | weight cast/reorder | stats zero ---
__global__ __launch_bounds__(256) void k_prep(const float* __restrict__ x,
                                              const float* __restrict__ w1,
                                              const float* __restrict__ w2,
                                              const float* __restrict__ w3,
                                              short* __restrict__ xb,
                                              short* __restrict__ w1b,
                                              short* __restrict__ w2b,
                                              short* __restrict__ w3b,
                                              float* __restrict__ statszero) {
  const int bid = blockIdx.x;
  if (bid < 2048) {
    __shared__ float tile[32][197];
    const int n = bid >> 5;
    const int c0 = (bid & 31) * 32;
    for (int idx = threadIdx.x; idx < 32 * 196; idx += 256) {
      int cl = idx / 196, hw = idx % 196;
      tile[cl][hw] = x[((size_t)(n * CIN + c0 + cl)) * HWSP + hw];
    }
    __syncthreads();
    for (int idx = threadIdx.x; idx < 196 * 32; idx += 256) {
      int hw = idx >> 5, cl = idx & 31;
      xb[((size_t)(n * HWSP + hw)) * CIN + c0 + cl] = f2bf(tile[cl][hw]);
    }
  } else if (bid < 6400) {
    int i = (bid - 2048) * 256 + threadIdx.x;
    if (i < 262144) w1b[i] = f2bf(w1[i]);
    int j = i - 262144;
    if (j >= 0 && j < 589824) {
      int co = j / 2304, rem = j % 2304;
      int d = rem >> 8, ci = rem & 255;
      w2b[j] = f2bf(w2[((size_t)(co * 256 + ci)) * 9 + d]);
    }
    int k = i - 851968;
    if (k >= 0 && k < 262144) w3b[k] = f2bf(w3[k]);
  } else {
    for (int k = threadIdx.x; k < 3136; k += 256) statszero[k] = 0.f;
  }
}

static __device__ __forceinline__ int swz(int row, int k16) {
  return row * 128 + (((unsigned)(k16 ^ (row & 7))) << 4);
}

// ---------------- 512-thread GEMM: 8 waves (2x4), same tile/bytes as R9 ------
// Tile 128x128x64, per-wave 64x32, acc[4][2]. Staged bytes per tile IDENTICAL
// to the 4-wave version; waves/CU doubles (1 -> 2 per SIMD) -> 2x outstanding
// loads + TLP at constant traffic. Loop = R9: stage(next); counted vmcnt(4)
// (retires exactly tile kt's 4 ops/thread); s_barrier; compute; s_barrier.
template <int MODE, int K>
__global__ __launch_bounds__(512) void gemm512(const short* __restrict__ A,
                                               const short* __restrict__ Bw,
                                               const float* __restrict__ bias,
                                               short* __restrict__ Yb,
                                               float* __restrict__ st,
                                               int Nc,
                                               const short* __restrict__ zerobuf) {
  __shared__ __align__(16) char lds[2][32768];  // per buf: A 16KB | B 16KB
  constexpr int NKT = K >> 6;

  const int m0 = blockIdx.x * 128;
  const int n0 = blockIdx.y * 128;
  const int t = threadIdx.x;
  const int lane = t & 63, wid = t >> 6;
  const int wm = wid >> 2, wn = wid & 3;    // 2x4 wave grid
  const int g = lane >> 4, r = lane & 15;

  // staging: A 1024 chunks + B 1024 chunks over 512 threads -> 2+2 per thread
  const short* aSrc[2];
  int aN[2], aH[2], aW[2], aCi[2];
  const short* bSrc[2];
#pragma unroll
  for (int q = 0; q < 2; ++q) {
    int chunk = t + q * 512;
    int row = chunk >> 3;
    int k16s = (chunk & 7) ^ (row & 7);
    if (MODE == 0) {
      aSrc[q] = A + (size_t)(m0 + row) * K + k16s * 8;
    } else {
      int m = m0 + row;
      int n_ = m / 196;
      int hw = m - n_ * 196;
      aN[q] = n_;
      aH[q] = hw / 14;
      aW[q] = hw - aH[q] * 14;
      aCi[q] = k16s * 8;
    }
    bSrc[q] = Bw + (size_t)(n0 + row) * K + k16s * 8;
  }

  auto stage = [&](int buf, int kt) {
    const int k0 = kt << 6;
    char* dA = &lds[buf][0];
    char* dB = &lds[buf][16384];
#pragma unroll
    for (int q = 0; q < 2; ++q) {
      const short* s;
      if (MODE == 0) {
        s = aSrc[q] + k0;
      } else {
        int d = kt >> 2;
        int dh = d / 3, dw = d - dh * 3;
        int hh = aH[q] + dh - 1, ww = aW[q] + dw - 1;
        s = ((unsigned)hh < 14u && (unsigned)ww < 14u)
                ? A + ((size_t)(aN[q] * 196 + hh * 14 + ww)) * 256 + (k0 & 255) + aCi[q]
                : zerobuf;
      }
      gload16(s, dA + (t + q * 512) * 16);
    }
#pragma unroll
    for (int q = 0; q < 2; ++q)
      gload16(bSrc[q] + k0, dB + (t + q * 512) * 16);
  };

  f32x4 acc[4][2] = {};
  auto compute = [&](int buf) {
    char* baseA = &lds[buf][0];
    char* baseB = &lds[buf][16384];
#pragma unroll
    for (int ks = 0; ks < 2; ++ks) {
      s16x8 af[4], bfr[2];
#pragma unroll
      for (int i = 0; i < 4; ++i)
        af[i] = *(const s16x8*)(baseA + swz(wm * 64 + i * 16 + r, ks * 4 + g));
#pragma unroll
      for (int j = 0; j < 2; ++j)
        bfr[j] = *(const s16x8*)(baseB + swz(wn * 32 + j * 16 + r, ks * 4 + g));
#pragma unroll
      for (int i = 0; i < 4; ++i)
#pragma unroll
        for (int j = 0; j < 2; ++j)
          acc[i][j] = __builtin_amdgcn_mfma_f32_16x16x32_bf16(af[i], bfr[j], acc[i][j], 0, 0, 0);
    }
  };

  stage(0, 0);
  int cur = 0;
#pragma unroll 1
  for (int kt = 0; kt < NKT - 1; ++kt) {
    stage(cur ^ 1, kt + 1);                            // 4 loads in flight
    asm volatile("s_waitcnt vmcnt(4)" ::: "memory");   // tile kt landed
    __builtin_amdgcn_s_barrier();
    compute(cur);
    asm volatile("" ::: "memory");
    __builtin_amdgcn_s_barrier();
    cur ^= 1;
  }
  asm volatile("s_waitcnt vmcnt(0)" ::: "memory");
  __builtin_amdgcn_s_barrier();
  compute(cur);

  // epilogue: bias, bf16 store, per-channel sum/sumsq -> atomics
#pragma unroll
  for (int j = 0; j < 2; ++j) {
    int col = n0 + wn * 32 + j * 16 + r;
    float bv = bias[col];
    float ps = 0.f, pq = 0.f;
#pragma unroll
    for (int i = 0; i < 4; ++i) {
      int row_base = m0 + wm * 64 + i * 16 + g * 4;
#pragma unroll
      for (int rr = 0; rr < 4; ++rr) {
        float v = acc[i][j][rr] + bv;
        ps += v;
        pq += v * v;
        Yb[(size_t)(row_base + rr) * Nc + col] = f2bf(v);
      }
    }
    ps += __shfl_xor(ps, 16);
    ps += __shfl_xor(ps, 32);
    pq += __shfl_xor(pq, 16);
    pq += __shfl_xor(pq, 32);
    if (lane < 16) {
      atomicAdd(&st[col], ps);
      atomicAdd(&st[Nc + col], pq);
    }
  }
}

// ---------------- 256-thread GEMM (R9) for conv3 -----------------------------
template <int MODE, int K>
__global__ __launch_bounds__(256) void gemm_kernel(const short* __restrict__ A,
                                                   const short* __restrict__ Bw,
                                                   const float* __restrict__ bias,
                                                   short* __restrict__ Yb,
                                                   float* __restrict__ st,
                                                   int Nc,
                                                   const short* __restrict__ zerobuf) {
  __shared__ __align__(16) char lds[2][32768];
  constexpr int NKT = K >> 6;

  const int m0 = blockIdx.x * 128;
  const int n0 = blockIdx.y * 128;
  const int t = threadIdx.x;
  const int lane = t & 63, wid = t >> 6;
  const int wm = wid >> 1, wn = wid & 1;
  const int g = lane >> 4, r = lane & 15;

  const short* aSrc[4];
  const short* bSrc[4];
#pragma unroll
  for (int q = 0; q < 4; ++q) {
    int chunk = t + q * 256;
    int row = chunk >> 3;
    int k16s = (chunk & 7) ^ (row & 7);
    aSrc[q] = A + (size_t)(m0 + row) * K + k16s * 8;
    bSrc[q] = Bw + (size_t)(n0 + row) * K + k16s * 8;
  }

  auto stage = [&](int buf, int kt) {
    const int k0 = kt << 6;
    char* dA = &lds[buf][0];
    char* dB = &lds[buf][16384];
#pragma unroll
    for (int q = 0; q < 4; ++q)
      gload16(aSrc[q] + k0, dA + (t + q * 256) * 16);
#pragma unroll
    for (int q = 0; q < 4; ++q)
      gload16(bSrc[q] + k0, dB + (t + q * 256) * 16);
  };

  f32x4 acc[4][4] = {};
  auto compute = [&](int buf) {
    char* baseA = &lds[buf][0];
    char* baseB = &lds[buf][16384];
#pragma unroll
    for (int ks = 0; ks < 2; ++ks) {
      s16x8 af[4], bfr[4];
#pragma unroll
      for (int i = 0; i < 4; ++i)
        af[i] = *(const s16x8*)(baseA + swz(wm * 64 + i * 16 + r, ks * 4 + g));
#pragma unroll
      for (int j = 0; j < 4; ++j)
        bfr[j] = *(const s16x8*)(baseB + swz(wn * 64 + j * 16 + r, ks * 4 + g));
#pragma unroll
      for (int i = 0; i < 4; ++i)
#pragma unroll
        for (int j = 0; j < 4; ++j)
          acc[i][j] = __builtin_amdgcn_mfma_f32_16x16x32_bf16(af[i], bfr[j], acc[i][j], 0, 0, 0);
    }
  };

  stage(0, 0);
  int cur = 0;
#pragma unroll 1
  for (int kt = 0; kt < NKT - 1; ++kt) {
    stage(cur ^ 1, kt + 1);
    asm volatile("s_waitcnt vmcnt(8)" ::: "memory");
    __builtin_amdgcn_s_barrier();
    compute(cur);
    asm volatile("" ::: "memory");
    __builtin_amdgcn_s_barrier();
    cur ^= 1;
  }
  asm volatile("s_waitcnt vmcnt(0)" ::: "memory");
  __builtin_amdgcn_s_barrier();
  compute(cur);

#pragma unroll
  for (int j = 0; j < 4; ++j) {
    int col = n0 + wn * 64 + j * 16 + r;
    float bv = bias[col];
    float ps = 0.f, pq = 0.f;
#pragma unroll
    for (int i = 0; i < 4; ++i) {
      int row_base = m0 + wm * 64 + i * 16 + g * 4;
#pragma unroll
      for (int rr = 0; rr < 4; ++rr) {
        float v = acc[i][j][rr] + bv;
        ps += v;
        pq += v * v;
        Yb[(size_t)(row_base + rr) * Nc + col] = f2bf(v);
      }
    }
    ps += __shfl_xor(ps, 16);
    ps += __shfl_xor(ps, 32);
    pq += __shfl_xor(pq, 16);
    pq += __shfl_xor(pq, 32);
    if (lane < 16) {
      atomicAdd(&st[col], ps);
      atomicAdd(&st[Nc + col], pq);
    }
  }
}

// ------- in-place: yb = bf16(relu(sc*yb+sh)), C=256; sc/sh computed here -----
__global__ __launch_bounds__(256) void k_apply(short* __restrict__ Yb,
                                               const float* __restrict__ st,
                                               const float* __restrict__ gamma,
                                               const float* __restrict__ beta) {
  __shared__ float lsc[256], lsh[256];
  const int t = threadIdx.x;
  {
    const float inv = 1.0f / 12544.0f;
    float mean = st[t] * inv;
    float var = st[256 + t] * inv - mean * mean;
    float s = gamma[t] * rsqrtf(var + 1e-5f);
    lsc[t] = s;
    lsh[t] = beta[t] - mean * s;
  }
  __syncthreads();
  size_t i8 = ((size_t)blockIdx.x * 256 + t) * 8;
  s16x8 v = *(const s16x8*)(Yb + i8);
  int c0 = (int)(i8 & 255);
#pragma unroll
  for (int e = 0; e < 8; ++e) {
    float f = bf2f(v[e]);
    v[e] = f2bf(fmaxf(lsc[c0 + e] * f + lsh[c0 + e], 0.f));
  }
  *(s16x8*)(Yb + i8) = v;
}

// -------- final: out = relu(x + softplus(rs)*bn3(y3)); sc/sh in-kernel -------
__global__ __launch_bounds__(256) void k_final(const float* __restrict__ x,
                                               const short* __restrict__ y3b,
                                               const float* __restrict__ st,
                                               const float* __restrict__ gamma,
                                               const float* __restrict__ beta,
                                               const float* __restrict__ rs,
                                               float* __restrict__ out) {
  __shared__ short ytile[64][198];
  __shared__ float lsc[64], lsh[64];
  const int n = blockIdx.x;
  const int co0 = blockIdx.y * 64;
  const int t = threadIdx.x;
  if (t < 64) {
    const float inv = 1.0f / 12544.0f;
    int c = co0 + t;
    float mean = st[c] * inv;
    float var = st[1024 + c] * inv - mean * mean;
    float s = gamma[c] * rsqrtf(var + 1e-5f);
    lsc[t] = s;
    lsh[t] = beta[c] - mean * s;
  }
#pragma unroll
  for (int iter = 0; iter < 49; ++iter) {
    int idx = iter * 256 + t;
    int hw = idx >> 6, c = idx & 63;
    ytile[c][hw] = y3b[((size_t)(n * 196 + hw)) * 1024 + co0 + c];
  }
  __syncthreads();
  float z = rs[0];
  float s = fmaxf(z, 0.f) + log1pf(expf(-fabsf(z)));  // stable softplus
#pragma unroll
  for (int iter = 0; iter < 49; ++iter) {
    int idx = iter * 256 + t;
    int co = idx / 196, hw = idx - co * 196;
    size_t xi = ((size_t)(n * 1024 + co0 + co)) * 196 + hw;
    float v = bf2f(ytile[co][hw]);
    float o = x[xi] + s * (lsc[co] * v + lsh[co]);
    out[xi] = fmaxf(o, 0.f);
  }
}

extern "C" void kernel_launch(void* const* d_in, const int* in_sizes, int n_in,
                              void* d_out, int out_size, void* d_ws, size_t ws_size,
                              hipStream_t stream) {
  const float* x   = (const float*)d_in[0];
  const float* w1  = (const float*)d_in[1];
  const float* b1  = (const float*)d_in[2];
  const float* g1  = (const float*)d_in[3];
  const float* be1 = (const float*)d_in[4];
  const float* w2  = (const float*)d_in[5];
  const float* b2  = (const float*)d_in[6];
  const float* g2  = (const float*)d_in[7];
  const float* be2 = (const float*)d_in[8];
  const float* w3  = (const float*)d_in[9];
  const float* b3  = (const float*)d_in[10];
  const float* g3  = (const float*)d_in[11];
  const float* be3 = (const float*)d_in[12];
  const float* rs  = (const float*)d_in[13];
  float* out = (float*)d_out;
  char* ws = (char*)d_ws;

  size_t off = 0;
  auto alloc = [&](size_t bytes) {
    size_t o = off;
    off += (bytes + 255) & ~(size_t)255;
    return o;
  };
  short* xb  = (short*)(ws + alloc((size_t)MTOT * CIN * 2));
  short* w1b = (short*)(ws + alloc((size_t)262144 * 2));
  short* w2b = (short*)(ws + alloc((size_t)589824 * 2));
  short* w3b = (short*)(ws + alloc((size_t)262144 * 2));
  short* y1b = (short*)(ws + alloc((size_t)MTOT * PL * 2));
  short* y2b = (short*)(ws + alloc((size_t)MTOT * PL * 2));
  short* y3b = (short*)(ws + alloc((size_t)MTOT * COUT * 2));
  float* stats = (float*)(ws + alloc(12288 + 256));
  float* stat1 = stats, *stat2 = stats + 512, *stat3 = stats + 1024;
  short* zerobuf = (short*)(stats + 3072);

  k_prep<<<6401, 256, 0, stream>>>(x, w1, w2, w3, xb, w1b, w2b, w3b, stats);

  // conv1: 1x1 reduce (K=1024 -> 256), 8-wave blocks, same tiles/bytes
  gemm512<0, 1024><<<dim3(98, 2), 512, 0, stream>>>(xb, w1b, b1, y1b, stat1, 256, zerobuf);
  k_apply<<<1568, 256, 0, stream>>>(y1b, stat1, g1, be1);

  // conv2: 3x3 (K=2304 -> 256), 8-wave blocks
  gemm512<1, 2304><<<dim3(98, 2), 512, 0, stream>>>(y1b, w2b, b2, y2b, stat2, 256, zerobuf);
  k_apply<<<1568, 256, 0, stream>>>(y2b, stat2, g2, be2);

  // conv3: 1x1 expand (K=256 -> 1024), 4-wave blocks (3 blocks/CU already)
  gemm_kernel<0, 256><<<dim3(98, 8), 256, 0, stream>>>(y2b, w3b, b3, y3b, stat3, 1024, zerobuf);

  // residual + relu (+ bn3 finalize in-kernel)
  k_final<<<dim3(64, 16), 256, 0, stream>>>(x, y3b, stat3, g3, be3, rs, out);
}